// Round 18
// baseline (78.819 us; speedup 1.0000x reference)
//
#include <hip/hip_runtime.h>

// Fused masked 3x3 conv x2 (MinkowskiConv stride-1 equivalent), fp32:
//   m   = float(mask)
//   h   = relu((conv3x3(x*m, w1) + b1) * m)
//   out = (conv3x3(h, w2) + b2) * m
// Round-17 compute (conv1 QUADS with aligned b128 taps, enc-sign mask
// folding, conv2 vertical register rolling, NT stores, XCD swizzle) +
// CROSS-TILE PIPELINE: each block does 2 vertically-adjacent tiles with
// double-buffered LDS. Tile-1's global loads are issued (branch-free,
// clamped, into registers) right after the first barrier, so their HBM/L2
// latency hides under conv1+conv2 of tile 0 (T14 issue-early/write-late).

#define TB_W 128           // output tile width
#define TB_H 16            // output tile height (per tile; block does 2)
#define SX   136           // staged width: TB_W + 8 (16B-aligned halo)
#define SY   20            // staged height: TB_H + 4
#define NV4  (SX / 4)      // 34 float4 chunks per staged row
#define NSTG (SY * NV4)    // 680
#define HR   18            // h rows per tile
#define NQR  33            // quads per h row
#define NQ   (HR * NQR)    // 594
#define IMG_W 2048
#define IMG_H 2048

__global__ __launch_bounds__(256) void fused_mconv2(
    const float* __restrict__ x, const int* __restrict__ mask,
    const float* __restrict__ w1p, const float* __restrict__ b1p,
    const float* __restrict__ w2p, const float* __restrict__ b2p,
    float* __restrict__ out)
{
    __shared__ __align__(16) float s_xm0[SY][SX], s_xm1[SY][SX];
    __shared__ __align__(16) float s_hm0[HR][SX], s_hm1[HR][SX];
    __shared__ __align__(4)  unsigned char s_mb0[HR][SX], s_mb1[HR][SX];

    // ---- XCD-chunked bijective swizzle (grid 8192 = 8 XCDs x 1024) ----
    // XCD k owns batch image k; 32-row band varies fastest -> vertical halo
    // re-reads are same-L2 hits.
    const int hw   = blockIdx.x;
    const int xcd  = hw & 7;
    const int slot = hw >> 3;                 // 0..1023
    const int orig = (xcd << 10) + slot;
    const int band = orig & 63;               // 0..63  (fastest)
    const int cl   = orig >> 6;
    const int tx   = cl & 15;                 // tile col 0..15
    const int tz   = cl >> 4;                 // batch 0..7 (== xcd)

    const int tid  = threadIdx.y * 64 + threadIdx.x;      // block (64,4)
    const int c0   = tx * TB_W;
    const int r0A  = band * (2 * TB_H);       // tile 0 rows
    const int r0B  = r0A + TB_H;              // tile 1 rows
    const size_t plane = (size_t)IMG_W * IMG_H;
    const float* xb = x    + (size_t)tz * plane;
    const int*   mb = mask + (size_t)tz * plane;
    float*       ob = out  + (size_t)tz * plane;

    float W1[9], W2[9];
    #pragma unroll
    for (int i = 0; i < 9; ++i) { W1[i] = w1p[i]; W2[i] = w2p[i]; }
    const float B1 = b1p[0], B2 = b2p[0];

    // ---- branch-free clamped load of one tile's stage region into regs ----
    float4 xrA[3]; int4 mrA[3];
    float4 xrB[3]; int4 mrB[3];
    auto issue_loads = [&](int r0t, float4* xr, int4* mr) {
        #pragma unroll
        for (int u = 0; u < 3; ++u) {
            const int idx  = tid + (u << 8);
            const int cidx = idx < NSTG ? idx : NSTG - 1;
            const int row  = cidx / NV4;
            const int col4 = cidx - row * NV4;
            int r = r0t - 2 + row;
            int c = c0 - 4 + (col4 << 2);
            r = r < 0 ? 0 : (r > IMG_H - 1 ? IMG_H - 1 : r);
            c = c < 0 ? 0 : (c > IMG_W - 4 ? IMG_W - 4 : c);
            const size_t g = (size_t)r * IMG_W + c;
            xr[u] = *reinterpret_cast<const float4*>(xb + g);
            mr[u] = *reinterpret_cast<const int4*>(mb + g);
        }
    };

    // ---- write staged regs into an LDS buffer (validity applied here) ----
    auto stage_write = [&](int r0t, const float4* xr, const int4* mr,
                           float (*sxm)[SX], unsigned char (*smb)[SX]) {
        #pragma unroll
        for (int u = 0; u < 3; ++u) {
            const int idx = tid + (u << 8);
            if (idx < NSTG) {
                const int row  = idx / NV4;
                const int col4 = idx - row * NV4;
                const int r = r0t - 2 + row;
                const int c = c0 - 4 + (col4 << 2);
                float4 xm = make_float4(0.f, 0.f, 0.f, 0.f);
                unsigned mpack = 0u;
                if (r >= 0 && r < IMG_H && c >= 0 && c < IMG_W) {
                    const float4 xv = xr[u];
                    const int4   mi = mr[u];
                    xm.x = mi.x ? xv.x : 0.f;
                    xm.y = mi.y ? xv.y : 0.f;
                    xm.z = mi.z ? xv.z : 0.f;
                    xm.w = mi.w ? xv.w : 0.f;
                    mpack = (mi.x ? 1u : 0u) | (mi.y ? 256u : 0u) |
                            (mi.z ? 65536u : 0u) | (mi.w ? 16777216u : 0u);
                }
                *reinterpret_cast<float4*>(&sxm[row][col4 << 2]) = xm;
                if (row >= 1 && row <= HR)
                    *reinterpret_cast<unsigned*>(&smb[row - 1][col4 << 2]) = mpack;
            }
        }
    };

    // ---- conv1 QUADS (R17) ----
    auto conv1 = [&](const float (*sxm)[SX], float (*shm)[SX],
                     const unsigned char (*smb)[SX]) {
        for (int idx = tid; idx < NQ; idx += 256) {
            const int hr = idx / NQR;
            const int q  = idx - hr * NQR;
            const int hc = q << 2;
            float a0 = B1, a1 = B1, a2 = B1, a3 = B1;
            #pragma unroll
            for (int di = 0; di < 3; ++di) {
                const float4 A  = *reinterpret_cast<const float4*>(&sxm[hr + di][hc]);
                const float4 Bv = *reinterpret_cast<const float4*>(&sxm[hr + di][hc + 4]);
                const float w0 = W1[di * 3], w1 = W1[di * 3 + 1], w2 = W1[di * 3 + 2];
                a0 += w0 * A.z  + w1 * A.w  + w2 * Bv.x;
                a1 += w0 * A.w  + w1 * Bv.x + w2 * Bv.y;
                a2 += w0 * Bv.x + w1 * Bv.y + w2 * Bv.z;
                a3 += w0 * Bv.y + w1 * Bv.z + w2 * Bv.w;
            }
            const unsigned mA = *reinterpret_cast<const unsigned*>(&smb[hr][hc]);
            const unsigned mB = *reinterpret_cast<const unsigned*>(&smb[hr][hc + 4]);
            float4 e;
            e.x = ((mA >> 24) & 255u) ? fmaxf(a0, 0.f) : -1.0f;
            e.y = ( mB        & 255u) ? fmaxf(a1, 0.f) : -1.0f;
            e.z = ((mB >>  8) & 255u) ? fmaxf(a2, 0.f) : -1.0f;
            e.w = ((mB >> 16) & 255u) ? fmaxf(a3, 0.f) : -1.0f;
            *reinterpret_cast<float4*>(&shm[hr][hc]) = e;
        }
    };

    // ---- conv2 vertical register rolling + NT stores (R17) ----
    auto conv2 = [&](const float (*shm)[SX], int r0t) {
        const int j     = tid & 127;
        const int strip = tid >> 7;          // 0..1
        const int i0    = strip * (TB_H / 2);
        float P = 0.f, Q = 0.f, cm = 0.f;
        #pragma unroll
        for (int t = 0; t < TB_H / 2 + 2; ++t) {
            const int hr = i0 + t;
            const float* rowp = &shm[hr][0];
            const float t0 = rowp[j];
            const float t1 = rowp[j + 1];
            const float t2 = rowp[j + 2];
            const float r0 = t0 > 0.f ? t0 : 0.f;
            const float r1 = t1 > 0.f ? t1 : 0.f;
            const float r2 = t2 > 0.f ? t2 : 0.f;
            const float d0 = W2[0] * r0 + W2[1] * r1 + W2[2] * r2;
            const float d1 = W2[3] * r0 + W2[4] * r1 + W2[5] * r2;
            const float d2 = W2[6] * r0 + W2[7] * r1 + W2[8] * r2;
            if (t >= 2) {
                const int i = i0 + t - 2;
                const float v = (cm >= 0.f) ? (Q + d2 + B2) : 0.f;
                __builtin_nontemporal_store(
                    v, ob + (size_t)(r0t + i) * IMG_W + (c0 + j));
            }
            Q  = P + d1;
            P  = d0;
            cm = t1;
        }
    };

    // ================= 2-tile pipelined schedule =================
    issue_loads(r0A, xrA, mrA);
    stage_write(r0A, xrA, mrA, s_xm0, s_mb0);
    __syncthreads();

    issue_loads(r0B, xrB, mrB);          // in flight under tile-0 compute
    conv1(s_xm0, s_hm0, s_mb0);
    __syncthreads();

    conv2(s_hm0, r0A);
    stage_write(r0B, xrB, mrB, s_xm1, s_mb1);   // loads landed by now
    __syncthreads();

    conv1(s_xm1, s_hm1, s_mb1);
    __syncthreads();

    conv2(s_hm1, r0B);
}

extern "C" void kernel_launch(void* const* d_in, const int* in_sizes, int n_in,
                              void* d_out, int out_size, void* d_ws, size_t ws_size,
                              hipStream_t stream) {
    const float* x    = (const float*)d_in[0];
    const int*   mask = (const int*)  d_in[1];
    const float* w1   = (const float*)d_in[2];
    const float* b1   = (const float*)d_in[3];
    const float* w2   = (const float*)d_in[4];
    const float* b2   = (const float*)d_in[5];
    float*       out  = (float*)d_out;

    dim3 block(64, 4, 1);
    dim3 grid(8192, 1, 1);               // 8 XCDs x 1024 (bijective swizzle)
    hipLaunchKernelGGL(fused_mconv2, grid, block, 0, stream,
                       x, mask, w1, b1, w2, b2, out);
}

// Round 20
// 72.035 us; speedup vs baseline: 1.0942x; 1.0942x over previous
//
#include <hip/hip_runtime.h>

// Fused masked 3x3 conv x2 (MinkowskiConv stride-1 equivalent), fp32 I/O:
//   m = float(mask); h = relu((conv3x3(x*m,w1)+b1)*m); out = (conv3x3(h,w2)+b2)*m
// R17 (conv1 quads, enc-sign folding, XCD swizzle, NT stores) + two LDS-pipe
// cuts (diagnosis: LDS pipe ~86% busy is the binding resource):
//  1. s_xm staged as BF16 (RTN): conv1 quad taps = 2x ds_read_b64 (was 2x b128);
//     fp32 accumulate. absmax budget 0.4325 >> bf16 error (~0.1).
//  2. conv2 as QUADS: 4 out cols/thread; enc words 4q..4q+5 via two ALIGNED
//     b128 reads; 8 strips x 2 rows, vertical register rolling; float4 NT
//     stores (via ext_vector_type — HIP float4 class is rejected by the
//     nontemporal builtin).
// LDS 17.7 KB -> 8 blocks/CU (32 waves, 100%).

#define TB_W 128
#define TB_H 16
#define SX   136           // staged width: TB_W + 8
#define SY   20            // staged height: TB_H + 4
#define NV4  (SX / 4)      // 34 chunks per staged row
#define NSTG (SY * NV4)    // 680
#define HR   18            // h rows
#define NQR  33            // conv1 quads per h row
#define NQ   (HR * NQR)    // 594
#define IMG_W 2048
#define IMG_H 2048

typedef float vf4 __attribute__((ext_vector_type(4)));

__device__ __forceinline__ unsigned pack_bf16_rtn(float a, float b) {
    unsigned ua = __float_as_uint(a), ub = __float_as_uint(b);
    ua = (ua + 0x8000u) >> 16;
    ub = (ub + 0x8000u) & 0xFFFF0000u;
    return ua | ub;
}
__device__ __forceinline__ float bf_lo(unsigned u) { return __uint_as_float(u << 16); }
__device__ __forceinline__ float bf_hi(unsigned u) { return __uint_as_float(u & 0xFFFF0000u); }

__global__ __launch_bounds__(256) void fused_mconv2(
    const float* __restrict__ x, const int* __restrict__ mask,
    const float* __restrict__ w1p, const float* __restrict__ b1p,
    const float* __restrict__ w2p, const float* __restrict__ b2p,
    float* __restrict__ out)
{
    __shared__ __align__(16) unsigned s_xm[SY][SX / 2];   // bf16 pairs (68 u32/row)
    __shared__ __align__(16) float    s_hm[HR][SX];       // enc(h,m) at word hcol
    __shared__ __align__(4)  unsigned char s_mb[HR][SX];  // mask bytes

    // ---- XCD-chunked bijective block swizzle (grid 16384 = 8 x 2048) ----
    const int hw   = (blockIdx.z * gridDim.y + blockIdx.y) * gridDim.x + blockIdx.x;
    const int xcd  = hw & 7;
    const int slot = hw >> 3;
    const int orig = (xcd << 11) + slot;      // XCD k owns [2048k, 2048k+2048)
    const int ty   = orig & 127;              // tile row (fastest)
    const int cl   = orig >> 7;
    const int tx   = cl & 15;                 // tile col
    const int tz   = cl >> 4;                 // batch (== xcd)

    const int tid  = threadIdx.y * 64 + threadIdx.x;
    const int c0   = tx * TB_W;
    const int row0 = ty * TB_H;
    const size_t plane = (size_t)IMG_W * IMG_H;
    const float* xb = x    + (size_t)tz * plane;
    const int*   mb = mask + (size_t)tz * plane;
    float*       ob = out  + (size_t)tz * plane;

    float W1[9], W2[9];
    #pragma unroll
    for (int i = 0; i < 9; ++i) { W1[i] = w1p[i]; W2[i] = w2p[i]; }
    const float B1 = b1p[0], B2 = b2p[0];

    // ---- stage: x*m as bf16 pairs + mask bytes, origin (row0-2, c0-4) ----
    for (int idx = tid; idx < NSTG; idx += 256) {
        const int row  = idx / NV4;
        const int col4 = idx - row * NV4;
        const int r = row0 - 2 + row;
        const int c = c0 - 4 + (col4 << 2);
        float4 xm = make_float4(0.f, 0.f, 0.f, 0.f);
        unsigned mpack = 0u;
        if (r >= 0 && r < IMG_H && c >= 0 && c < IMG_W) {   // all-or-nothing 16B
            const size_t g = (size_t)r * IMG_W + c;
            const float4 xv = *reinterpret_cast<const float4*>(xb + g);
            const int4   mi = *reinterpret_cast<const int4*>(mb + g);
            xm.x = mi.x ? xv.x : 0.f;
            xm.y = mi.y ? xv.y : 0.f;
            xm.z = mi.z ? xv.z : 0.f;
            xm.w = mi.w ? xv.w : 0.f;
            mpack = (mi.x ? 1u : 0u) | (mi.y ? 256u : 0u) |
                    (mi.z ? 65536u : 0u) | (mi.w ? 16777216u : 0u);
        }
        uint2 p;
        p.x = pack_bf16_rtn(xm.x, xm.y);
        p.y = pack_bf16_rtn(xm.z, xm.w);
        *reinterpret_cast<uint2*>(&s_xm[row][col4 << 1]) = p;   // 8B aligned
        if (row >= 1 && row <= HR)
            *reinterpret_cast<unsigned*>(&s_mb[row - 1][col4 << 2]) = mpack;
    }
    __syncthreads();

    // ---- conv1 QUADS (bf16 taps): 4 points/thread ----
    // Quad hc=4q: points hc..hc+3 tap stage cols hc+2..hc+7; read pairs
    // [2q..2q+1] and [2q+2..2q+3] as two uint2 (8B aligned).
    for (int idx = tid; idx < NQ; idx += 256) {
        const int hr = idx / NQR;
        const int q  = idx - hr * NQR;
        const int hc = q << 2;
        float a0 = B1, a1 = B1, a2 = B1, a3 = B1;
        #pragma unroll
        for (int di = 0; di < 3; ++di) {
            const unsigned* xr = &s_xm[hr + di][q << 1];
            const uint2 A  = *reinterpret_cast<const uint2*>(xr);
            const uint2 Bv = *reinterpret_cast<const uint2*>(xr + 2);
            const float c2 = bf_lo(A.y),  c3 = bf_hi(A.y);
            const float c4 = bf_lo(Bv.x), c5 = bf_hi(Bv.x);
            const float c6 = bf_lo(Bv.y), c7 = bf_hi(Bv.y);
            const float w0 = W1[di * 3], w1 = W1[di * 3 + 1], w2 = W1[di * 3 + 2];
            a0 += w0 * c2 + w1 * c3 + w2 * c4;
            a1 += w0 * c3 + w1 * c4 + w2 * c5;
            a2 += w0 * c4 + w1 * c5 + w2 * c6;
            a3 += w0 * c5 + w1 * c6 + w2 * c7;
        }
        const unsigned mA = *reinterpret_cast<const unsigned*>(&s_mb[hr][hc]);
        const unsigned mB = *reinterpret_cast<const unsigned*>(&s_mb[hr][hc + 4]);
        float4 e;
        e.x = ((mA >> 24) & 255u) ? fmaxf(a0, 0.f) : -1.0f;
        e.y = ( mB        & 255u) ? fmaxf(a1, 0.f) : -1.0f;
        e.z = ((mB >>  8) & 255u) ? fmaxf(a2, 0.f) : -1.0f;
        e.w = ((mB >> 16) & 255u) ? fmaxf(a3, 0.f) : -1.0f;
        *reinterpret_cast<float4*>(&s_hm[hr][hc]) = e;   // 16B aligned
    }
    __syncthreads();

    // ---- conv2 QUADS: 4 out cols/thread, 2 aligned b128/row, rolling ----
    // out(i, 4q+c) taps s_hm rows i..i+2, words 4q+c..4q+c+2 (c=0..3) ->
    // words 4q..4q+5 from float4 at [4q] and [4q+4]. 8 strips x 2 rows.
    {
        const int q     = tid & 31;          // quad -> out cols 4q..4q+3
        const int strip = tid >> 5;          // 0..7
        const int i0    = strip << 1;        // out rows i0, i0+1
        const int jc    = q << 2;
        float P[4] = {0,0,0,0}, Q[4] = {0,0,0,0}, cm[4] = {0,0,0,0};
        #pragma unroll
        for (int t = 0; t < 4; ++t) {
            const int hr = i0 + t;
            const float4 E1 = *reinterpret_cast<const float4*>(&s_hm[hr][jc]);
            const float4 E2 = *reinterpret_cast<const float4*>(&s_hm[hr][jc + 4]);
            const float v0 = E1.x, v1 = E1.y, v2 = E1.z, v3 = E1.w;
            const float v4 = E2.x, v5 = E2.y;
            const float r0 = fmaxf(v0, 0.f), r1 = fmaxf(v1, 0.f);
            const float r2 = fmaxf(v2, 0.f), r3 = fmaxf(v3, 0.f);
            const float r4 = fmaxf(v4, 0.f), r5 = fmaxf(v5, 0.f);
            float d0[4], d1[4], d2[4];
            d0[0] = W2[0]*r0 + W2[1]*r1 + W2[2]*r2;
            d0[1] = W2[0]*r1 + W2[1]*r2 + W2[2]*r3;
            d0[2] = W2[0]*r2 + W2[1]*r3 + W2[2]*r4;
            d0[3] = W2[0]*r3 + W2[1]*r4 + W2[2]*r5;
            d1[0] = W2[3]*r0 + W2[4]*r1 + W2[5]*r2;
            d1[1] = W2[3]*r1 + W2[4]*r2 + W2[5]*r3;
            d1[2] = W2[3]*r2 + W2[4]*r3 + W2[5]*r4;
            d1[3] = W2[3]*r3 + W2[4]*r4 + W2[5]*r5;
            d2[0] = W2[6]*r0 + W2[7]*r1 + W2[8]*r2;
            d2[1] = W2[6]*r1 + W2[7]*r2 + W2[8]*r3;
            d2[2] = W2[6]*r2 + W2[7]*r3 + W2[8]*r4;
            d2[3] = W2[6]*r3 + W2[7]*r4 + W2[8]*r5;
            if (t >= 2) {
                const int i = i0 + t - 2;
                vf4 o;
                o.x = (cm[0] >= 0.f) ? (Q[0] + d2[0] + B2) : 0.f;
                o.y = (cm[1] >= 0.f) ? (Q[1] + d2[1] + B2) : 0.f;
                o.z = (cm[2] >= 0.f) ? (Q[2] + d2[2] + B2) : 0.f;
                o.w = (cm[3] >= 0.f) ? (Q[3] + d2[3] + B2) : 0.f;
                __builtin_nontemporal_store(
                    o, reinterpret_cast<vf4*>(
                           ob + (size_t)(row0 + i) * IMG_W + (c0 + jc)));
            }
            #pragma unroll
            for (int c = 0; c < 4; ++c) { Q[c] = P[c] + d1[c]; P[c] = d0[c]; }
            cm[0] = v1; cm[1] = v2; cm[2] = v3; cm[3] = v4;   // enc centers
        }
    }
}

extern "C" void kernel_launch(void* const* d_in, const int* in_sizes, int n_in,
                              void* d_out, int out_size, void* d_ws, size_t ws_size,
                              hipStream_t stream) {
    const float* x    = (const float*)d_in[0];
    const int*   mask = (const int*)  d_in[1];
    const float* w1   = (const float*)d_in[2];
    const float* b1   = (const float*)d_in[3];
    const float* w2   = (const float*)d_in[4];
    const float* b2   = (const float*)d_in[5];
    float*       out  = (float*)d_out;

    dim3 block(64, 4, 1);
    dim3 grid(IMG_W / TB_W, IMG_H / TB_H, 8);   // 16 x 128 x 8 = 16384
    hipLaunchKernelGGL(fused_mconv2, grid, block, 0, stream,
                       x, mask, w1, b1, w2, b2, out);
}